// Round 1
// baseline (343.138 us; speedup 1.0000x reference)
//
#include <hip/hip_runtime.h>
#include <stdint.h>

typedef __attribute__((ext_vector_type(8))) short bf16x8;
typedef __attribute__((ext_vector_type(4))) float f32x4;
typedef __attribute__((ext_vector_type(8))) unsigned short u16x8;

#define N_IMG 32
#define CI 256
#define CO 256
#define HH_ 56
#define WW_ 56
#define HP 58
#define WP 58
#define SPP (HP*WP)   /* 3364 padded spatial */
#define SPI (HH_*WW_) /* 3136 */

#define XB_BYTES ((size_t)N_IMG*SPP*CI*2)   /* 55,115,776 */
#define W2_OFF   XB_BYTES
#define W2_BYTES ((size_t)9*CO*CI*2)        /* 1,179,648 */
#define SCALE_OFF (W2_OFF + W2_BYTES)

#define KCP 40   /* padded LDS row: 32 bf16 + 8 pad -> 80B stride, ~2-way conflicts (free) */

// ---------------- prep 1: zero padded NHWC buffer ----------------
__global__ __launch_bounds__(256) void zero_xb_k(uint4* __restrict__ p) {
  p[(size_t)blockIdx.x*256 + threadIdx.x] = make_uint4(0u,0u,0u,0u);
}

// ---------------- prep 2: NCHW fp32 -> padded NHWC bf16 ----------------
__global__ __launch_bounds__(256) void nchw2nhwc_k(const float* __restrict__ x,
                                                   unsigned short* __restrict__ xb) {
  __shared__ float tile[64*33];
  int b = blockIdx.x;
  int n = b / 392; int r = b - n*392;          // 392 = 8 c-chunks * 49 sp-tiles
  int cc = r / 49; int t0 = (r - cc*49) * 64;  // spatial tile base (flat, 3136/64=49)
  int t = threadIdx.x;
  int sp = t & 63; int ci4 = t >> 6;
  const float* src = x + ((size_t)(n*CI + cc*32))*SPI + t0;
#pragma unroll
  for (int i = 0; i < 8; ++i) {
    int c = i*4 + ci4;
    tile[sp*33 + c] = src[(size_t)c*SPI + sp];   // coalesced read along sp
  }
  __syncthreads();
  int osp = t >> 2; int cg = t & 3;
  int spg = t0 + osp;
  int h = spg / 56; int w = spg - h*56;
  int psp = (h+1)*58 + (w+1);                   // padded coords
  unsigned int pk[4];
#pragma unroll
  for (int j = 0; j < 4; ++j) {
    unsigned int u0 = __builtin_bit_cast(unsigned int, tile[osp*33 + cg*8 + j*2]);
    unsigned int u1 = __builtin_bit_cast(unsigned int, tile[osp*33 + cg*8 + j*2 + 1]);
    u0 = (u0 + 0x7fffu + ((u0 >> 16) & 1u)) >> 16;   // RNE f32->bf16
    u1 = (u1 + 0x7fffu + ((u1 >> 16) & 1u)) >> 16;
    pk[j] = u0 | (u1 << 16);
  }
  uint4 v; v.x = pk[0]; v.y = pk[1]; v.z = pk[2]; v.w = pk[3];
  *(uint4*)(&xb[((size_t)n*SPP + psp)*CI + cc*32 + cg*8]) = v;  // 16B, c-contiguous
}

// ---------------- prep 3: scale[o] = mean|w|; W2[tap][o][c] = bf16(sign(w)) ----------------
__global__ __launch_bounds__(256) void prep_w_k(const float* __restrict__ wt,
                                                unsigned short* __restrict__ w2,
                                                float* __restrict__ scale) {
  int o = blockIdx.x; int t = threadIdx.x;
  float s = 0.f;
#pragma unroll
  for (int k = t, it = 0; it < 9; ++it, k += 256) {   // 2304 = 9*256 exact
    float v = wt[(size_t)o*2304 + k];
    s += fabsf(v);
    int c = k / 9; int tap = k - c*9;
    unsigned short sg = (v > 0.f) ? (unsigned short)0x3F80u
                       : ((v < 0.f) ? (unsigned short)0xBF80u : (unsigned short)0u);
    w2[((size_t)tap*CO + o)*CI + c] = sg;
  }
  __shared__ float red[4];
#pragma unroll
  for (int off = 32; off > 0; off >>= 1) s += __shfl_down(s, off, 64);
  if ((t & 63) == 0) red[t >> 6] = s;
  __syncthreads();
  if (t == 0) scale[o] = (red[0]+red[1]+red[2]+red[3]) * (1.0f/2304.0f);
}

// ---------------- main: implicit-GEMM MFMA conv ----------------
// block: 64 o x 224 pixels (8h x 28w); 4 waves = 2(o) x 2(pix); wave: 32o x 112pix
// K loop: 8 chunks of 32 channels x 9 taps; MFMA 16x16x32 bf16
__global__ __launch_bounds__(256, 2) void binconv_k(
    const unsigned short* __restrict__ xb,
    const unsigned short* __restrict__ w2,
    const float* __restrict__ scale,
    float* __restrict__ out) {
  __shared__ unsigned short s_patch[300*KCP];  // [10h][30w][40c] 24,000 B
  __shared__ unsigned short s_w[576*KCP];      // [9tap][64o][40c] 46,080 B

  int bid = blockIdx.x;
  int ot = bid & 3; int pt = bid >> 2;
  int n = pt / 14; int rem = pt - n*14;        // 14 = 7 h-tiles * 2 w-tiles
  int ht = rem >> 1; int wt = rem & 1;
  int h0 = ht*8, w0 = wt*28, ob = ot*64;
  int tid = threadIdx.x;
  int lane = tid & 63, wid = tid >> 6;
  int wo = wid >> 1, wp = wid & 1;
  int lrow = lane & 15, lgrp = lane >> 4;

  // per-lane B-fragment base offsets (elements) into s_patch (tap adds (dh*30+dw)*KCP)
  int pb[7];
#pragma unroll
  for (int f = 0; f < 7; ++f) {
    int p = wp*112 + f*16 + lrow;              // pixel index in 8x28 tile, p = th*28+tw
    int th = p / 28; int tw = p - th*28;
    pb[f] = (th*30 + tw)*KCP + lgrp*8;
  }
  int ab0 = (wo*32 + lrow)*KCP + lgrp*8;       // A base (m adds 16*KCP, tap adds 64*KCP)

  f32x4 acc[2][7];
#pragma unroll
  for (int m = 0; m < 2; ++m)
#pragma unroll
    for (int f = 0; f < 7; ++f) {
      f32x4 z = {0.f, 0.f, 0.f, 0.f};
      acc[m][f] = z;
    }

  const size_t xbase = ((size_t)n*SPP + (size_t)h0*WP + w0)*CI;

  for (int cc = 0; cc < 8; ++cc) {
    __syncthreads();
    // stage x halo patch: 300 rows x 32c = 1200 x 16B
#pragma unroll
    for (int u = tid, it = 0; it < 5; ++it, u += 256) {
      if (u < 1200) {
        int rr = u >> 2, cg = u & 3;
        int hh = rr / 30, ww2 = rr - hh*30;
        *(u16x8*)&s_patch[rr*KCP + cg*8] =
          *(const u16x8*)&xb[xbase + ((size_t)hh*WP + ww2)*CI + (size_t)cc*32 + cg*8];
      }
    }
    // stage weights: 9*64 rows x 32c = 2304 x 16B
#pragma unroll
    for (int u = tid, it = 0; it < 9; ++it, u += 256) {
      int tap = u >> 8, r2 = u & 255, oo = r2 >> 2, cg = r2 & 3;
      *(u16x8*)&s_w[(tap*64 + oo)*KCP + cg*8] =
        *(const u16x8*)&w2[((size_t)tap*CO + ob + oo)*CI + (size_t)cc*32 + cg*8];
    }
    __syncthreads();
#pragma unroll
    for (int tap = 0; tap < 9; ++tap) {
      const int dh = tap / 3, dw = tap - dh*3;
      const int toff = (dh*30 + dw)*KCP;
      const int woff = tap*64*KCP;
      bf16x8 a0 = *(const bf16x8*)&s_w[woff + ab0];
      bf16x8 a1 = *(const bf16x8*)&s_w[woff + ab0 + 16*KCP];
      bf16x8 bv[7];
#pragma unroll
      for (int f = 0; f < 7; ++f)
        bv[f] = *(const bf16x8*)&s_patch[pb[f] + toff];
#pragma unroll
      for (int f = 0; f < 7; ++f) {
        acc[0][f] = __builtin_amdgcn_mfma_f32_16x16x32_bf16(a0, bv[f], acc[0][f], 0, 0, 0);
        acc[1][f] = __builtin_amdgcn_mfma_f32_16x16x32_bf16(a1, bv[f], acc[1][f], 0, 0, 0);
      }
    }
  }

  // epilogue: scale (fp32) + store NCHW
  float sc[2][4];
#pragma unroll
  for (int m = 0; m < 2; ++m)
#pragma unroll
    for (int r = 0; r < 4; ++r)
      sc[m][r] = scale[ob + wo*32 + m*16 + lgrp*4 + r];

#pragma unroll
  for (int f = 0; f < 7; ++f) {
    int p = wp*112 + f*16 + lrow;
    int th = p / 28; int tw = p - th*28;
    size_t spo = (size_t)(h0+th)*WW_ + (w0+tw);
#pragma unroll
    for (int m = 0; m < 2; ++m) {
      int o = ob + wo*32 + m*16 + lgrp*4;
      float* dst = out + ((size_t)n*CO + o)*SPI + spo;
#pragma unroll
      for (int r = 0; r < 4; ++r)
        dst[(size_t)r*SPI] = acc[m][f][r] * sc[m][r];
    }
  }
}

extern "C" void kernel_launch(void* const* d_in, const int* in_sizes, int n_in,
                              void* d_out, int out_size, void* d_ws, size_t ws_size,
                              hipStream_t stream) {
  const float* x  = (const float*)d_in[0];
  const float* wt = (const float*)d_in[1];
  float* out = (float*)d_out;
  unsigned short* xb = (unsigned short*)d_ws;
  unsigned short* w2 = (unsigned short*)((char*)d_ws + W2_OFF);
  float* scale = (float*)((char*)d_ws + SCALE_OFF);

  // 55,115,776 B / 16 / 256 = 13,456 blocks exactly
  zero_xb_k<<<13456, 256, 0, stream>>>((uint4*)d_ws);
  nchw2nhwc_k<<<12544, 256, 0, stream>>>(x, xb);     // 32n * 8cc * 49 tiles
  prep_w_k<<<256, 256, 0, stream>>>(wt, w2, scale);
  binconv_k<<<1792, 256, 0, stream>>>(xb, w2, scale, out);  // 448 pix-tiles * 4 o-tiles
}